// Round 8
// baseline (283.752 us; speedup 1.0000x reference)
//
#include <hip/hip_runtime.h>
#include <hip/hip_bf16.h>
#include <math.h>

#define N_ROWS 65536
#define PSI    1024
#define DDIM   256

typedef _Float16       half8 __attribute__((ext_vector_type(8)));
typedef _Float16       half4 __attribute__((ext_vector_type(4)));
typedef float          f32x4 __attribute__((ext_vector_type(4)));
typedef unsigned short us8   __attribute__((ext_vector_type(8)));

// ---------- async global->LDS, 16B per lane ----------
__device__ __forceinline__ void gload16(const void* g, void* l) {
    __builtin_amdgcn_global_load_lds(
        (const __attribute__((address_space(1))) unsigned int*)g,
        (__attribute__((address_space(3))) unsigned int*)l, 16, 0, 0);
}

// bf16 round-to-nearest-even from f32
__device__ __forceinline__ unsigned short f2bf(float f) {
    unsigned u = __float_as_uint(f);
    u += 0x7FFFu + ((u >> 16) & 1u);
    return (unsigned short)(u >> 16);
}

// ---------- convert f32 -> f16 + row squared-norms (f32-exact) ----------
__global__ __launch_bounds__(256) void k_convert(
    const float* __restrict__ in, _Float16* __restrict__ outh,
    float* __restrict__ nrm, int rows)
{
    const int wave = (blockIdx.x * blockDim.x + threadIdx.x) >> 6;
    const int lane = threadIdx.x & 63;
    if (wave >= rows) return;
    const float4 v = *(const float4*)&in[(size_t)wave * DDIM + lane * 4];
    float s = v.x * v.x + v.y * v.y + v.z * v.z + v.w * v.w;
    #pragma unroll
    for (int o = 32; o > 0; o >>= 1) s += __shfl_down(s, o);
    if (lane == 0) nrm[wave] = s;
    half4 h;
    h[0] = (_Float16)v.x; h[1] = (_Float16)v.y;
    h[2] = (_Float16)v.z; h[3] = (_Float16)v.w;
    *(half4*)&outh[(size_t)wave * DDIM + lane * 4] = h;
}

// ---------- MFMA GEMM, 128x128 tile, BK=64, double-buffered, swizzled LDS ---
// Shift-free softmax: u = exp(-m), m = sqrt(max(x2+s2-2*dot,0))*w.
// m in ~[15,30] for this data -> u in [1e-13, 1]: f32/bf16 exponent range OK
// (f16 would FLUSH TO ZERO: min subnormal 6e-8 > typical u ~ 1e-10).
// XCD-chunked 1D grid (4096): each XCD owns 64 row-panels x 8 col-blocks.
// LDS: [row][k] 128B rows, XOR-swizzle byte^=((row&7)<<4) applied as
// pre-swizzled GLOBAL k-chunk on stage + XOR'd ds_read (both-sides rule).
// MODE 0: column partial sums of u only               (path B pass 1)
// MODE 1: recompute, out = u * rs[c]                  (path B pass 2)
// MODE 2: column partial sums + NT-store u as bf16    (path A single GEMM)
template<int MODE>
__global__ __launch_bounds__(256) void k_gemm(
    const _Float16* __restrict__ Xh, const _Float16* __restrict__ Sh,
    const float* __restrict__ x2, const float* __restrict__ s2,
    const float* __restrict__ w,
    float* __restrict__ ps, const float* __restrict__ rs,
    float* __restrict__ out, unsigned short* __restrict__ uh)
{
    __shared__ _Float16 As[2][128 * 64];   // 2 x 16 KB
    __shared__ _Float16 Bs[2][128 * 64];   // 2 x 16 KB

    const int tid  = threadIdx.x;
    const int wv   = tid >> 6;
    const int wr   = wv >> 1;       // wave row half (0..1)
    const int wc   = wv & 1;        // wave col half (0..1)
    const int l15  = tid & 15;
    const int l4   = (tid & 63) >> 4;

    // XCD swizzle (nwg=4096 divisible by 8 -> bijective)
    const int fid   = blockIdx.x;
    const int wgid  = (fid & 7) * 512 + (fid >> 3);
    const int rowb  = wgid >> 3;            // 0..511
    const int row0  = rowb * 128;
    const int col0  = (wgid & 7) * 128;

    f32x4 acc[4][4];
    #pragma unroll
    for (int i = 0; i < 4; ++i)
        #pragma unroll
        for (int j = 0; j < 4; ++j) acc[i][j] = (f32x4){0.f, 0.f, 0.f, 0.f};

    // staging: lane tid covers row tid>>3 (of 32-row group), pre-swizzled
    // k-chunk ((tid&7)^((tid>>3)&7))*8 halfs. 8 lanes cover one 128B row.
    const int srow = tid >> 3;
    const int skq  = ((tid & 7) ^ (srow & 7)) * 8;
    const _Float16* gAp = Xh + (size_t)(row0 + srow) * DDIM + skq;
    const _Float16* gBp = Sh + (size_t)(col0 + srow) * DDIM + skq;

    auto stage = [&](int k0, int b) {
        _Float16* Ab = &As[b][wv * 512];
        _Float16* Bb = &Bs[b][wv * 512];
        #pragma unroll
        for (int rg = 0; rg < 4; ++rg)
            gload16(gAp + (size_t)(rg * 32) * DDIM + k0, Ab + rg * 2048);
        #pragma unroll
        for (int rg = 0; rg < 4; ++rg)
            gload16(gBp + (size_t)(rg * 32) * DDIM + k0, Bb + rg * 2048);
    };

    auto compute = [&](int b) {
        #pragma unroll
        for (int kk = 0; kk < 2; ++kk) {
            half8 af[4], bf[4];
            #pragma unroll
            for (int f = 0; f < 4; ++f) {
                const int swz = (l15 & 7) << 3;               // halfs
                const int ha = ((wr * 64 + f * 16 + l15) * 64 + kk * 32 + l4 * 8) ^ swz;
                const int hb = ((wc * 64 + f * 16 + l15) * 64 + kk * 32 + l4 * 8) ^ swz;
                af[f] = *(const half8*)&As[b][ha];
                bf[f] = *(const half8*)&Bs[b][hb];
            }
            #pragma unroll
            for (int fm = 0; fm < 4; ++fm)
                #pragma unroll
                for (int fn = 0; fn < 4; ++fn)
                    acc[fm][fn] = __builtin_amdgcn_mfma_f32_16x16x32_f16(
                        af[fm], bf[fn], acc[fm][fn], 0, 0, 0);
        }
    };

    stage(0, 0);
    __syncthreads();
    #pragma unroll
    for (int t = 0; t < 4; ++t) {           // K = 4 x 64
        if (t < 3) stage((t + 1) * 64, (t + 1) & 1);
        compute(t & 1);
        if (t < 3) __syncthreads();
    }

    // ---- epilogue ----
    float4 x2r[4];
    #pragma unroll
    for (int fm = 0; fm < 4; ++fm)
        x2r[fm] = *(const float4*)&x2[row0 + wr * 64 + fm * 16 + l4 * 4];

    if (MODE == 0 || MODE == 2) {
        __syncthreads();                       // As dead -> alias sum array
        float* s_sm = (float*)&As[0][0];
        if (tid < 128) s_sm[tid] = 0.0f;
        __syncthreads();
        #pragma unroll
        for (int fn = 0; fn < 4; ++fn) {
            const int cl = wc * 64 + fn * 16 + l15;
            const int c  = col0 + cl;
            const float s2c = s2[c], ww = w[c];
            float s = 0.0f;
            #pragma unroll
            for (int fm = 0; fm < 4; ++fm) {
                const float* xr = (const float*)&x2r[fm];
                const int rbase = row0 + wr * 64 + fm * 16 + l4 * 4;
                #pragma unroll
                for (int j = 0; j < 4; ++j) {
                    float d2 = xr[j] + s2c - 2.0f * acc[fm][fn][j];
                    float u  = __expf(-sqrtf(fmaxf(d2, 0.0f)) * ww);
                    s += u;
                    if (MODE == 2)
                        __builtin_nontemporal_store(f2bf(u),
                            &uh[(size_t)(rbase + j) * PSI + c]);
                }
            }
            // reduce over the 4 l4 row-groups (lane bits 4,5)
            s += __shfl_xor(s, 16);
            s += __shfl_xor(s, 32);
            if (l4 == 0) atomicAdd(&s_sm[cl], s);   // 2 waves (wr) contend
        }
        __syncthreads();
        if (tid < 128) ps[(size_t)rowb * PSI + col0 + tid] = s_sm[tid];
    } else {
        #pragma unroll
        for (int fn = 0; fn < 4; ++fn) {
            const int c = col0 + wc * 64 + fn * 16 + l15;
            const float s2c = s2[c], ww = w[c];
            const float rsc = rs[c];
            #pragma unroll
            for (int fm = 0; fm < 4; ++fm) {
                const float* xr = (const float*)&x2r[fm];
                const int rbase = row0 + wr * 64 + fm * 16 + l4 * 4;
                #pragma unroll
                for (int j = 0; j < 4; ++j) {
                    float d2 = xr[j] + s2c - 2.0f * acc[fm][fn][j];
                    float u  = __expf(-sqrtf(fmaxf(d2, 0.0f)) * ww) * rsc;
                    __builtin_nontemporal_store(u, &out[(size_t)(rbase + j) * PSI + c]);
                }
            }
        }
    }
}

// ---------- path A pass 2: out[e] = bf16_to_f32(uh[e]) * rs[e & 1023] -------
__global__ __launch_bounds__(256) void k_scale(
    const unsigned short* __restrict__ uh, const float* __restrict__ rs,
    float* __restrict__ out)
{
    const size_t total8 = (size_t)N_ROWS * PSI / 8;       // 8,388,608
    const size_t stride = (size_t)gridDim.x * blockDim.x; // 524,288
    size_t i = (size_t)blockIdx.x * blockDim.x + threadIdx.x;
    // column octet invariant: stride*8 % 1024 == 0
    const int c0 = (int)((i * 8) & 1023);
    float r[8];
    #pragma unroll
    for (int j = 0; j < 8; ++j) r[j] = rs[c0 + j];
    f32x4* outv = (f32x4*)out;
    for (; i < total8; i += stride) {
        us8 h = __builtin_nontemporal_load((const us8*)uh + i);
        f32x4 lo, hi;
        lo[0] = __uint_as_float((unsigned)h[0] << 16) * r[0];
        lo[1] = __uint_as_float((unsigned)h[1] << 16) * r[1];
        lo[2] = __uint_as_float((unsigned)h[2] << 16) * r[2];
        lo[3] = __uint_as_float((unsigned)h[3] << 16) * r[3];
        hi[0] = __uint_as_float((unsigned)h[4] << 16) * r[4];
        hi[1] = __uint_as_float((unsigned)h[5] << 16) * r[5];
        hi[2] = __uint_as_float((unsigned)h[6] << 16) * r[6];
        hi[3] = __uint_as_float((unsigned)h[7] << 16) * r[7];
        __builtin_nontemporal_store(lo, outv + i * 2);
        __builtin_nontemporal_store(hi, outv + i * 2 + 1);
    }
}

// ---------- combine stage 1: 8 chunks x 64 bands, 32 blocks ----------
__global__ __launch_bounds__(256) void k_combine1(
    const float* __restrict__ ps, float* __restrict__ ps2)
{
    const int g     = blockIdx.x * 256 + threadIdx.x;   // [0, 8192)
    const int col   = g & 1023;
    const int chunk = g >> 10;                          // [0, 8)
    const int b0    = chunk * 64;
    float t = 0.0f;
    #pragma unroll 4
    for (int b = 0; b < 64; ++b)
        t += ps[(size_t)(b0 + b) * PSI + col];
    ps2[(size_t)chunk * PSI + col] = t;
}

// ---------- combine stage 2: rs = 1 / total sum ----------
__global__ __launch_bounds__(256) void k_combine2(
    const float* __restrict__ ps2, float* __restrict__ rs)
{
    const int col = blockIdx.x * 256 + threadIdx.x;   // grid 4
    float t = 0.0f;
    #pragma unroll
    for (int b = 0; b < 8; ++b)
        t += ps2[(size_t)b * PSI + col];
    rs[col] = 1.0f / t;
}

extern "C" void kernel_launch(void* const* d_in, const int* in_sizes, int n_in,
                              void* d_out, int out_size, void* d_ws, size_t ws_size,
                              hipStream_t stream) {
    const float* X = (const float*)d_in[0];
    const float* S = (const float*)d_in[1];
    const float* w = (const float*)d_in[2];
    float* out = (float*)d_out;

    char* ws = (char*)d_ws;
    // Path A layout (needs ~170.7 MB): uh first, then the small buffers.
    const size_t UH_BYTES = (size_t)N_ROWS * PSI * 2;     // 134,217,728
    const size_t NEED_A   = UH_BYTES + 36479040;          // + path-B working set

    if (ws_size >= NEED_A) {
        unsigned short* uh = (unsigned short*)ws;
        char* base = ws + UH_BYTES;
        _Float16* Xh  = (_Float16*)(base);                 // 33,554,432 B
        _Float16* Sh  = (_Float16*)(base + 33554432);      //    524,288 B
        float*    x2  = (float*)   (base + 34078720);      //    262,144 B
        float*    s2  = (float*)   (base + 34340864);      //      4,096 B
        float*    ps  = (float*)   (base + 34344960);      //  2,097,152 B
        float*    ps2 = (float*)   (base + 36442112);      //     32,768 B
        float*    rs  = (float*)   (base + 36474880);      //      4,096 B

        k_convert<<<dim3(N_ROWS / 4), dim3(256), 0, stream>>>(X, Xh, x2, N_ROWS);
        k_convert<<<dim3(PSI / 4),    dim3(256), 0, stream>>>(S, Sh, s2, PSI);
        k_gemm<2><<<dim3(4096), dim3(256), 0, stream>>>(
            Xh, Sh, x2, s2, w, ps, nullptr, nullptr, uh);
        k_combine1<<<dim3(32), dim3(256), 0, stream>>>(ps, ps2);
        k_combine2<<<dim3(PSI / 256), dim3(256), 0, stream>>>(ps2, rs);
        k_scale<<<dim3(2048), dim3(256), 0, stream>>>(uh, rs, out);
    } else {
        _Float16* Xh  = (_Float16*)(ws);                   // 33,554,432 B
        _Float16* Sh  = (_Float16*)(ws + 33554432);        //    524,288 B
        float*    x2  = (float*)   (ws + 34078720);        //    262,144 B
        float*    s2  = (float*)   (ws + 34340864);        //      4,096 B
        float*    ps  = (float*)   (ws + 34344960);        //  2,097,152 B
        float*    ps2 = (float*)   (ws + 36442112);        //     32,768 B
        float*    rs  = (float*)   (ws + 36474880);        //      4,096 B

        k_convert<<<dim3(N_ROWS / 4), dim3(256), 0, stream>>>(X, Xh, x2, N_ROWS);
        k_convert<<<dim3(PSI / 4),    dim3(256), 0, stream>>>(S, Sh, s2, PSI);
        k_gemm<0><<<dim3(4096), dim3(256), 0, stream>>>(
            Xh, Sh, x2, s2, w, ps, nullptr, nullptr, nullptr);
        k_combine1<<<dim3(32), dim3(256), 0, stream>>>(ps, ps2);
        k_combine2<<<dim3(PSI / 256), dim3(256), 0, stream>>>(ps2, rs);
        k_gemm<1><<<dim3(4096), dim3(256), 0, stream>>>(
            Xh, Sh, x2, s2, w, nullptr, rs, out, nullptr);
    }
}

// Round 9
// 211.027 us; speedup vs baseline: 1.3446x; 1.3446x over previous
//
#include <hip/hip_runtime.h>
#include <hip/hip_bf16.h>
#include <math.h>

#define N_ROWS 65536
#define PSI    1024
#define DDIM   256

typedef _Float16       half8 __attribute__((ext_vector_type(8)));
typedef _Float16       half4 __attribute__((ext_vector_type(4)));
typedef float          f32x4 __attribute__((ext_vector_type(4)));
typedef unsigned short us8   __attribute__((ext_vector_type(8)));

// ---------- async global->LDS, 16B per lane ----------
__device__ __forceinline__ void gload16(const void* g, void* l) {
    __builtin_amdgcn_global_load_lds(
        (const __attribute__((address_space(1))) unsigned int*)g,
        (__attribute__((address_space(3))) unsigned int*)l, 16, 0, 0);
}

// bf16 round-to-nearest-even from f32
__device__ __forceinline__ unsigned short f2bf(float f) {
    unsigned u = __float_as_uint(f);
    u += 0x7FFFu + ((u >> 16) & 1u);
    return (unsigned short)(u >> 16);
}

// ---------- convert f32 -> f16 + row squared-norms (f32-exact) ----------
__global__ __launch_bounds__(256) void k_convert(
    const float* __restrict__ in, _Float16* __restrict__ outh,
    float* __restrict__ nrm, int rows)
{
    const int wave = (blockIdx.x * blockDim.x + threadIdx.x) >> 6;
    const int lane = threadIdx.x & 63;
    if (wave >= rows) return;
    const float4 v = *(const float4*)&in[(size_t)wave * DDIM + lane * 4];
    float s = v.x * v.x + v.y * v.y + v.z * v.z + v.w * v.w;
    #pragma unroll
    for (int o = 32; o > 0; o >>= 1) s += __shfl_down(s, o);
    if (lane == 0) nrm[wave] = s;
    half4 h;
    h[0] = (_Float16)v.x; h[1] = (_Float16)v.y;
    h[2] = (_Float16)v.z; h[3] = (_Float16)v.w;
    *(half4*)&outh[(size_t)wave * DDIM + lane * 4] = h;
}

// ---------- MFMA GEMM, 128x128 tile, BK=64, double-buffered, swizzled LDS ---
// Shift-free softmax: u = exp(-m), m = sqrt(max(x2+s2-2*dot,0))*w.
// m in ~[15,30] -> u in [1e-13, 1]: bf16/f32 exponent range OK (f16 would
// flush to zero). MODE 2 stores u-bf16 via an LDS transpose: the fragment
// layout's 2B column-scattered stores caused 38% write amplification and
// 168us (round 8); staging the 128x128 bf16 tile in the dead A-dbuf and
// re-emitting as 16B lane-contiguous NT stores makes the write coalesced.
// MODE 0: column partial sums of u only               (path B pass 1)
// MODE 1: recompute, out = u * rs[c]                  (path B pass 2)
// MODE 2: column partial sums + coalesced u-bf16 dump (path A single GEMM)
template<int MODE>
__global__ __launch_bounds__(256) void k_gemm(
    const _Float16* __restrict__ Xh, const _Float16* __restrict__ Sh,
    const float* __restrict__ x2, const float* __restrict__ s2,
    const float* __restrict__ w,
    float* __restrict__ ps, const float* __restrict__ rs,
    float* __restrict__ out, unsigned short* __restrict__ uh)
{
    __shared__ _Float16 As[2][128 * 64];   // 2 x 16 KB (epilogue: u-tile)
    __shared__ _Float16 Bs[2][128 * 64];   // 2 x 16 KB (epilogue: s_sm)

    const int tid  = threadIdx.x;
    const int wv   = tid >> 6;
    const int wr   = wv >> 1;       // wave row half (0..1)
    const int wc   = wv & 1;        // wave col half (0..1)
    const int l15  = tid & 15;
    const int l4   = (tid & 63) >> 4;

    // XCD swizzle (nwg=4096 divisible by 8 -> bijective)
    const int fid   = blockIdx.x;
    const int wgid  = (fid & 7) * 512 + (fid >> 3);
    const int rowb  = wgid >> 3;            // 0..511
    const int row0  = rowb * 128;
    const int col0  = (wgid & 7) * 128;

    f32x4 acc[4][4];
    #pragma unroll
    for (int i = 0; i < 4; ++i)
        #pragma unroll
        for (int j = 0; j < 4; ++j) acc[i][j] = (f32x4){0.f, 0.f, 0.f, 0.f};

    // staging: lane tid covers row tid>>3 (of 32-row group), pre-swizzled
    // k-chunk ((tid&7)^((tid>>3)&7))*8 halfs. 8 lanes cover one 128B row.
    const int srow = tid >> 3;
    const int skq  = ((tid & 7) ^ (srow & 7)) * 8;
    const _Float16* gAp = Xh + (size_t)(row0 + srow) * DDIM + skq;
    const _Float16* gBp = Sh + (size_t)(col0 + srow) * DDIM + skq;

    auto stage = [&](int k0, int b) {
        _Float16* Ab = &As[b][wv * 512];
        _Float16* Bb = &Bs[b][wv * 512];
        #pragma unroll
        for (int rg = 0; rg < 4; ++rg)
            gload16(gAp + (size_t)(rg * 32) * DDIM + k0, Ab + rg * 2048);
        #pragma unroll
        for (int rg = 0; rg < 4; ++rg)
            gload16(gBp + (size_t)(rg * 32) * DDIM + k0, Bb + rg * 2048);
    };

    auto compute = [&](int b) {
        #pragma unroll
        for (int kk = 0; kk < 2; ++kk) {
            half8 af[4], bf[4];
            #pragma unroll
            for (int f = 0; f < 4; ++f) {
                const int swz = (l15 & 7) << 3;               // halfs
                const int ha = ((wr * 64 + f * 16 + l15) * 64 + kk * 32 + l4 * 8) ^ swz;
                const int hb = ((wc * 64 + f * 16 + l15) * 64 + kk * 32 + l4 * 8) ^ swz;
                af[f] = *(const half8*)&As[b][ha];
                bf[f] = *(const half8*)&Bs[b][hb];
            }
            #pragma unroll
            for (int fm = 0; fm < 4; ++fm)
                #pragma unroll
                for (int fn = 0; fn < 4; ++fn)
                    acc[fm][fn] = __builtin_amdgcn_mfma_f32_16x16x32_f16(
                        af[fm], bf[fn], acc[fm][fn], 0, 0, 0);
        }
    };

    stage(0, 0);
    __syncthreads();
    #pragma unroll
    for (int t = 0; t < 4; ++t) {           // K = 4 x 64
        if (t < 3) stage((t + 1) * 64, (t + 1) & 1);
        compute(t & 1);
        if (t < 3) __syncthreads();
    }

    // ---- epilogue ----
    float4 x2r[4];
    #pragma unroll
    for (int fm = 0; fm < 4; ++fm)
        x2r[fm] = *(const float4*)&x2[row0 + wr * 64 + fm * 16 + l4 * 4];

    if (MODE == 0 || MODE == 2) {
        __syncthreads();                     // As/Bs dead -> reuse
        unsigned short* ut = (unsigned short*)&As[0][0];   // [128][128] bf16
        float*          s_sm = (float*)&Bs[0][0];          // 128 col sums
        if (tid < 128) s_sm[tid] = 0.0f;
        __syncthreads();
        #pragma unroll
        for (int fn = 0; fn < 4; ++fn) {
            const int cl = wc * 64 + fn * 16 + l15;
            const int c  = col0 + cl;
            const float s2c = s2[c], ww = w[c];
            float s = 0.0f;
            #pragma unroll
            for (int fm = 0; fm < 4; ++fm) {
                const float* xr = (const float*)&x2r[fm];
                const int lrow = wr * 64 + fm * 16 + l4 * 4;
                #pragma unroll
                for (int j = 0; j < 4; ++j) {
                    float d2 = xr[j] + s2c - 2.0f * acc[fm][fn][j];
                    float u  = __expf(-sqrtf(fmaxf(d2, 0.0f)) * ww);
                    s += u;
                    if (MODE == 2) ut[(lrow + j) * 128 + cl] = f2bf(u);
                }
            }
            // reduce over the 4 l4 row-groups (lane bits 4,5)
            s += __shfl_xor(s, 16);
            s += __shfl_xor(s, 32);
            if (l4 == 0) atomicAdd(&s_sm[cl], s);   // 2 waves (wr) contend
        }
        __syncthreads();
        if (MODE == 2) {
            // coalesced dump: 8 iters, 16B/lane, 256B contiguous per 16 lanes
            const int lr = tid >> 4;          // 0..15
            const int lc = tid & 15;          // 0..15
            #pragma unroll
            for (int k = 0; k < 8; ++k) {
                const int row = lr + k * 16;
                us8 v = *(const us8*)&ut[row * 128 + lc * 8];
                __builtin_nontemporal_store(v,
                    (us8*)&uh[(size_t)(row0 + row) * PSI + col0 + lc * 8]);
            }
        }
        if (tid < 128) ps[(size_t)rowb * PSI + col0 + tid] = s_sm[tid];
    } else {
        #pragma unroll
        for (int fn = 0; fn < 4; ++fn) {
            const int c = col0 + wc * 64 + fn * 16 + l15;
            const float s2c = s2[c], ww = w[c];
            const float rsc = rs[c];
            #pragma unroll
            for (int fm = 0; fm < 4; ++fm) {
                const float* xr = (const float*)&x2r[fm];
                const int rbase = row0 + wr * 64 + fm * 16 + l4 * 4;
                #pragma unroll
                for (int j = 0; j < 4; ++j) {
                    float d2 = xr[j] + s2c - 2.0f * acc[fm][fn][j];
                    float u  = __expf(-sqrtf(fmaxf(d2, 0.0f)) * ww) * rsc;
                    __builtin_nontemporal_store(u, &out[(size_t)(rbase + j) * PSI + c]);
                }
            }
        }
    }
}

// ---------- path A pass 2: out[e] = bf16_to_f32(uh[e]) * rs[e & 1023] -------
__global__ __launch_bounds__(256) void k_scale(
    const unsigned short* __restrict__ uh, const float* __restrict__ rs,
    float* __restrict__ out)
{
    const size_t total8 = (size_t)N_ROWS * PSI / 8;       // 8,388,608
    const size_t stride = (size_t)gridDim.x * blockDim.x; // 524,288
    size_t i = (size_t)blockIdx.x * blockDim.x + threadIdx.x;
    // column octet invariant: stride*8 % 1024 == 0
    const int c0 = (int)((i * 8) & 1023);
    float r[8];
    #pragma unroll
    for (int j = 0; j < 8; ++j) r[j] = rs[c0 + j];
    f32x4* outv = (f32x4*)out;
    for (; i < total8; i += stride) {
        us8 h = *((const us8*)uh + i);
        f32x4 lo, hi;
        lo[0] = __uint_as_float((unsigned)h[0] << 16) * r[0];
        lo[1] = __uint_as_float((unsigned)h[1] << 16) * r[1];
        lo[2] = __uint_as_float((unsigned)h[2] << 16) * r[2];
        lo[3] = __uint_as_float((unsigned)h[3] << 16) * r[3];
        hi[0] = __uint_as_float((unsigned)h[4] << 16) * r[4];
        hi[1] = __uint_as_float((unsigned)h[5] << 16) * r[5];
        hi[2] = __uint_as_float((unsigned)h[6] << 16) * r[6];
        hi[3] = __uint_as_float((unsigned)h[7] << 16) * r[7];
        __builtin_nontemporal_store(lo, outv + i * 2);
        __builtin_nontemporal_store(hi, outv + i * 2 + 1);
    }
}

// ---------- combine stage 1: 8 chunks x 64 bands, 32 blocks ----------
__global__ __launch_bounds__(256) void k_combine1(
    const float* __restrict__ ps, float* __restrict__ ps2)
{
    const int g     = blockIdx.x * 256 + threadIdx.x;   // [0, 8192)
    const int col   = g & 1023;
    const int chunk = g >> 10;                          // [0, 8)
    const int b0    = chunk * 64;
    float t = 0.0f;
    #pragma unroll 4
    for (int b = 0; b < 64; ++b)
        t += ps[(size_t)(b0 + b) * PSI + col];
    ps2[(size_t)chunk * PSI + col] = t;
}

// ---------- combine stage 2: rs = 1 / total sum ----------
__global__ __launch_bounds__(256) void k_combine2(
    const float* __restrict__ ps2, float* __restrict__ rs)
{
    const int col = blockIdx.x * 256 + threadIdx.x;   // grid 4
    float t = 0.0f;
    #pragma unroll
    for (int b = 0; b < 8; ++b)
        t += ps2[(size_t)b * PSI + col];
    rs[col] = 1.0f / t;
}

extern "C" void kernel_launch(void* const* d_in, const int* in_sizes, int n_in,
                              void* d_out, int out_size, void* d_ws, size_t ws_size,
                              hipStream_t stream) {
    const float* X = (const float*)d_in[0];
    const float* S = (const float*)d_in[1];
    const float* w = (const float*)d_in[2];
    float* out = (float*)d_out;

    char* ws = (char*)d_ws;
    // Path A layout (needs ~170.7 MB): uh first, then the small buffers.
    const size_t UH_BYTES = (size_t)N_ROWS * PSI * 2;     // 134,217,728
    const size_t NEED_A   = UH_BYTES + 36479040;          // + path-B working set

    if (ws_size >= NEED_A) {
        unsigned short* uh = (unsigned short*)ws;
        char* base = ws + UH_BYTES;
        _Float16* Xh  = (_Float16*)(base);                 // 33,554,432 B
        _Float16* Sh  = (_Float16*)(base + 33554432);      //    524,288 B
        float*    x2  = (float*)   (base + 34078720);      //    262,144 B
        float*    s2  = (float*)   (base + 34340864);      //      4,096 B
        float*    ps  = (float*)   (base + 34344960);      //  2,097,152 B
        float*    ps2 = (float*)   (base + 36442112);      //     32,768 B
        float*    rs  = (float*)   (base + 36474880);      //      4,096 B

        k_convert<<<dim3(N_ROWS / 4), dim3(256), 0, stream>>>(X, Xh, x2, N_ROWS);
        k_convert<<<dim3(PSI / 4),    dim3(256), 0, stream>>>(S, Sh, s2, PSI);
        k_gemm<2><<<dim3(4096), dim3(256), 0, stream>>>(
            Xh, Sh, x2, s2, w, ps, nullptr, nullptr, uh);
        k_combine1<<<dim3(32), dim3(256), 0, stream>>>(ps, ps2);
        k_combine2<<<dim3(PSI / 256), dim3(256), 0, stream>>>(ps2, rs);
        k_scale<<<dim3(2048), dim3(256), 0, stream>>>(uh, rs, out);
    } else {
        _Float16* Xh  = (_Float16*)(ws);                   // 33,554,432 B
        _Float16* Sh  = (_Float16*)(ws + 33554432);        //    524,288 B
        float*    x2  = (float*)   (ws + 34078720);        //    262,144 B
        float*    s2  = (float*)   (ws + 34340864);        //      4,096 B
        float*    ps  = (float*)   (ws + 34344960);        //  2,097,152 B
        float*    ps2 = (float*)   (ws + 36442112);        //     32,768 B
        float*    rs  = (float*)   (ws + 36474880);        //      4,096 B

        k_convert<<<dim3(N_ROWS / 4), dim3(256), 0, stream>>>(X, Xh, x2, N_ROWS);
        k_convert<<<dim3(PSI / 4),    dim3(256), 0, stream>>>(S, Sh, s2, PSI);
        k_gemm<0><<<dim3(4096), dim3(256), 0, stream>>>(
            Xh, Sh, x2, s2, w, ps, nullptr, nullptr, nullptr);
        k_combine1<<<dim3(32), dim3(256), 0, stream>>>(ps, ps2);
        k_combine2<<<dim3(PSI / 256), dim3(256), 0, stream>>>(ps2, rs);
        k_gemm<1><<<dim3(4096), dim3(256), 0, stream>>>(
            Xh, Sh, x2, s2, w, nullptr, rs, out, nullptr);
    }
}

// Round 10
// 185.384 us; speedup vs baseline: 1.5306x; 1.1383x over previous
//
#include <hip/hip_runtime.h>
#include <hip/hip_bf16.h>
#include <math.h>

#define N_ROWS 65536
#define PSI    1024
#define DDIM   256

typedef _Float16       half8 __attribute__((ext_vector_type(8)));
typedef _Float16       half4 __attribute__((ext_vector_type(4)));
typedef float          f32x4 __attribute__((ext_vector_type(4)));

// ---------- async global->LDS, 16B per lane ----------
__device__ __forceinline__ void gload16(const void* g, void* l) {
    __builtin_amdgcn_global_load_lds(
        (const __attribute__((address_space(1))) unsigned int*)g,
        (__attribute__((address_space(3))) unsigned int*)l, 16, 0, 0);
}

// ---------- convert f32 -> f16 + row squared-norms (f32-exact) ----------
__global__ __launch_bounds__(256) void k_convert(
    const float* __restrict__ in, _Float16* __restrict__ outh,
    float* __restrict__ nrm, int rows)
{
    const int wave = (blockIdx.x * blockDim.x + threadIdx.x) >> 6;
    const int lane = threadIdx.x & 63;
    if (wave >= rows) return;
    const float4 v = *(const float4*)&in[(size_t)wave * DDIM + lane * 4];
    float s = v.x * v.x + v.y * v.y + v.z * v.z + v.w * v.w;
    #pragma unroll
    for (int o = 32; o > 0; o >>= 1) s += __shfl_down(s, o);
    if (lane == 0) nrm[wave] = s;
    half4 h;
    h[0] = (_Float16)v.x; h[1] = (_Float16)v.y;
    h[2] = (_Float16)v.z; h[3] = (_Float16)v.w;
    *(half4*)&outh[(size_t)wave * DDIM + lane * 4] = h;
}

// ---------- MFMA GEMM, 128x128 tile, BK=32, double-buffered, 32KB LDS ------
// Occupancy lever: 32 KB LDS + launch_bounds(256,4) -> 4 blocks/CU (16
// waves/CU); barrier/vmcnt drains hide under other resident blocks (m114).
// Shift-free softmax: u = exp(-m), m = sqrt(max(x2+s2-2*dot,0))*w; m>=0,
// bounded -> no max-shift needed (softmax shift-invariance; f32 range ok).
// LDS rows are 64B (4x16B chunks); swizzle chunk ^= (row>>1)&3 applied
// BOTH-sides (pre-swizzled global k-chunk + XOR'd ds_read). Bank check:
// bank = parity(row)*16 + 4*(chunk^((row>>1)&3)) -> 16 lanes on 8 banks,
// 2-way aliasing = free.
// XCD-chunked 1D grid (4096): each XCD owns 64 row-panels x 8 col-blocks.
// MODE 0: per-128-row-band column partial sums of u -> ps
// MODE 1: out = u * rs[c]   (nontemporal stream)
template<int MODE>
__global__ __launch_bounds__(256, 4) void k_gemm(
    const _Float16* __restrict__ Xh, const _Float16* __restrict__ Sh,
    const float* __restrict__ x2, const float* __restrict__ s2,
    const float* __restrict__ w,
    float* __restrict__ ps, const float* __restrict__ rs,
    float* __restrict__ out)
{
    __shared__ _Float16 As[2][128 * 32];   // 2 x 8 KB
    __shared__ _Float16 Bs[2][128 * 32];   // 2 x 8 KB

    const int tid  = threadIdx.x;
    const int wv   = tid >> 6;
    const int wr   = wv >> 1;       // wave row half (0..1)
    const int wc   = wv & 1;        // wave col half (0..1)
    const int l15  = tid & 15;
    const int l4   = (tid & 63) >> 4;

    // XCD swizzle (nwg=4096 divisible by 8 -> bijective)
    const int fid   = blockIdx.x;
    const int wgid  = (fid & 7) * 512 + (fid >> 3);
    const int rowb  = wgid >> 3;            // 0..511
    const int row0  = rowb * 128;
    const int col0  = (wgid & 7) * 128;

    f32x4 acc[4][4];
    #pragma unroll
    for (int i = 0; i < 4; ++i)
        #pragma unroll
        for (int j = 0; j < 4; ++j) acc[i][j] = (f32x4){0.f, 0.f, 0.f, 0.f};

    // staging: thread covers rows rg*64 + (tid>>2), chunk tid&3 (16B chunks
    // of a 64B row). Pre-swizzled global k-chunk = (tid&3) ^ ((srow>>1)&3)
    // (row bit6 of rg*64 doesn't touch (row>>1)&3).
    const int srow = tid >> 2;              // 0..63
    const int skq  = ((tid & 3) ^ ((srow >> 1) & 3)) * 8;
    const _Float16* gAp = Xh + (size_t)(row0 + srow) * DDIM + skq;
    const _Float16* gBp = Sh + (size_t)(col0 + srow) * DDIM + skq;

    auto stage = [&](int k0, int b) {
        _Float16* Ab = &As[b][wv * 512];
        _Float16* Bb = &Bs[b][wv * 512];
        #pragma unroll
        for (int rg = 0; rg < 2; ++rg)
            gload16(gAp + (size_t)(rg * 64) * DDIM + k0, Ab + rg * 2048);
        #pragma unroll
        for (int rg = 0; rg < 2; ++rg)
            gload16(gBp + (size_t)(rg * 64) * DDIM + k0, Bb + rg * 2048);
    };

    auto compute = [&](int b) {
        half8 af[4], bf[4];
        #pragma unroll
        for (int f = 0; f < 4; ++f) {
            const int ra = wr * 64 + f * 16 + l15;
            const int rb = wc * 64 + f * 16 + l15;
            const int ha = (ra * 32 + l4 * 8) ^ (((ra >> 1) & 3) << 3);
            const int hb = (rb * 32 + l4 * 8) ^ (((rb >> 1) & 3) << 3);
            af[f] = *(const half8*)&As[b][ha];
            bf[f] = *(const half8*)&Bs[b][hb];
        }
        #pragma unroll
        for (int fm = 0; fm < 4; ++fm)
            #pragma unroll
            for (int fn = 0; fn < 4; ++fn)
                acc[fm][fn] = __builtin_amdgcn_mfma_f32_16x16x32_f16(
                    af[fm], bf[fn], acc[fm][fn], 0, 0, 0);
    };

    stage(0, 0);
    __syncthreads();
    #pragma unroll
    for (int t = 0; t < 8; ++t) {           // K = 8 x 32
        if (t < 7) stage((t + 1) * 32, (t + 1) & 1);
        compute(t & 1);
        if (t < 7) __syncthreads();
    }

    // ---- epilogue ----
    float4 x2r[4];
    #pragma unroll
    for (int fm = 0; fm < 4; ++fm)
        x2r[fm] = *(const float4*)&x2[row0 + wr * 64 + fm * 16 + l4 * 4];

    if (MODE == 0) {
        __syncthreads();                       // As dead -> alias sum array
        float* s_sm = (float*)&As[0][0];
        if (tid < 128) s_sm[tid] = 0.0f;
        __syncthreads();
        #pragma unroll
        for (int fn = 0; fn < 4; ++fn) {
            const int cl = wc * 64 + fn * 16 + l15;
            const int c  = col0 + cl;
            const float s2c = s2[c], ww = w[c];
            float s = 0.0f;
            #pragma unroll
            for (int fm = 0; fm < 4; ++fm) {
                const float* xr = (const float*)&x2r[fm];
                #pragma unroll
                for (int j = 0; j < 4; ++j) {
                    float d2 = xr[j] + s2c - 2.0f * acc[fm][fn][j];
                    s += __expf(-sqrtf(fmaxf(d2, 0.0f)) * ww);
                }
            }
            // reduce over the 4 l4 row-groups (lane bits 4,5)
            s += __shfl_xor(s, 16);
            s += __shfl_xor(s, 32);
            if (l4 == 0) atomicAdd(&s_sm[cl], s);   // 2 waves (wr) contend
        }
        __syncthreads();
        if (tid < 128) ps[(size_t)rowb * PSI + col0 + tid] = s_sm[tid];
    } else {
        #pragma unroll
        for (int fn = 0; fn < 4; ++fn) {
            const int c = col0 + wc * 64 + fn * 16 + l15;
            const float s2c = s2[c], ww = w[c];
            const float rsc = rs[c];
            #pragma unroll
            for (int fm = 0; fm < 4; ++fm) {
                const float* xr = (const float*)&x2r[fm];
                const int rbase = row0 + wr * 64 + fm * 16 + l4 * 4;
                #pragma unroll
                for (int j = 0; j < 4; ++j) {
                    float d2 = xr[j] + s2c - 2.0f * acc[fm][fn][j];
                    float u  = __expf(-sqrtf(fmaxf(d2, 0.0f)) * ww) * rsc;
                    __builtin_nontemporal_store(u, &out[(size_t)(rbase + j) * PSI + c]);
                }
            }
        }
    }
}

// ---------- combine stage 1: 8 chunks x 64 bands, 32 blocks ----------
__global__ __launch_bounds__(256) void k_combine1(
    const float* __restrict__ ps, float* __restrict__ ps2)
{
    const int g     = blockIdx.x * 256 + threadIdx.x;   // [0, 8192)
    const int col   = g & 1023;
    const int chunk = g >> 10;                          // [0, 8)
    const int b0    = chunk * 64;
    float t = 0.0f;
    #pragma unroll 4
    for (int b = 0; b < 64; ++b)
        t += ps[(size_t)(b0 + b) * PSI + col];
    ps2[(size_t)chunk * PSI + col] = t;
}

// ---------- combine stage 2: rs = 1 / total sum ----------
__global__ __launch_bounds__(256) void k_combine2(
    const float* __restrict__ ps2, float* __restrict__ rs)
{
    const int col = blockIdx.x * 256 + threadIdx.x;   // grid 4
    float t = 0.0f;
    #pragma unroll
    for (int b = 0; b < 8; ++b)
        t += ps2[(size_t)b * PSI + col];
    rs[col] = 1.0f / t;
}

extern "C" void kernel_launch(void* const* d_in, const int* in_sizes, int n_in,
                              void* d_out, int out_size, void* d_ws, size_t ws_size,
                              hipStream_t stream) {
    const float* X = (const float*)d_in[0];
    const float* S = (const float*)d_in[1];
    const float* w = (const float*)d_in[2];
    float* out = (float*)d_out;

    char* ws = (char*)d_ws;
    _Float16* Xh  = (_Float16*)(ws);                   // 33,554,432 B
    _Float16* Sh  = (_Float16*)(ws + 33554432);        //    524,288 B
    float*    x2  = (float*)   (ws + 34078720);        //    262,144 B
    float*    s2  = (float*)   (ws + 34340864);        //      4,096 B
    float*    ps  = (float*)   (ws + 34344960);        //  2,097,152 B
    float*    ps2 = (float*)   (ws + 36442112);        //     32,768 B
    float*    rs  = (float*)   (ws + 36474880);        //      4,096 B

    k_convert<<<dim3(N_ROWS / 4), dim3(256), 0, stream>>>(X, Xh, x2, N_ROWS);
    k_convert<<<dim3(PSI / 4),    dim3(256), 0, stream>>>(S, Sh, s2, PSI);
    k_gemm<0><<<dim3(4096), dim3(256), 0, stream>>>(
        Xh, Sh, x2, s2, w, ps, nullptr, nullptr);
    k_combine1<<<dim3(32), dim3(256), 0, stream>>>(ps, ps2);
    k_combine2<<<dim3(PSI / 256), dim3(256), 0, stream>>>(ps2, rs);
    k_gemm<1><<<dim3(4096), dim3(256), 0, stream>>>(
        Xh, Sh, x2, s2, w, nullptr, rs, out);
}